// Round 1
// baseline (996.707 us; speedup 1.0000x reference)
//
#include <hip/hip_runtime.h>

// Problem: B=16, K=64, L=M=128, D=768, fp32 in, fp32 out (B*K=1024 scalars).
// out[bk] = sum_l max_m <ctx[bk,l,:], ent[bk,m,:]>
//
// One workgroup per bk. 1024 blocks = 4 blocks/CU * 256 CUs exactly.
// D staged in 12 chunks of 64, fp32 -> bf16 into LDS, 16x16x32 bf16 MFMA.

typedef __attribute__((ext_vector_type(8))) __bf16 bf16x8;
typedef __attribute__((ext_vector_type(4))) __bf16 bf16x4;
typedef __attribute__((ext_vector_type(4))) float f32x4;

#define L_DIM 128
#define D_DIM 768
#define DC    64          // D-chunk
#define LDP   72          // padded LDS row (bf16 elems): 64 + 8 -> 144 B rows, 16B-aligned frags

__global__ __launch_bounds__(256, 4)
void som_kernel(const float* __restrict__ context, float* __restrict__ out) {
    const int bk   = blockIdx.x;
    const int t    = threadIdx.x;
    const int lane = t & 63;
    const int wave = t >> 6;
    const int quad = (lane >> 4) & 3;   // 0..3
    const int l15  = lane & 15;

    const float* ctx_g = context + (size_t)bk * (2 * L_DIM * D_DIM);
    const float* ent_g = ctx_g + (size_t)(L_DIM * D_DIM);

    __shared__ __bf16 ctx_s[L_DIM * LDP];
    __shared__ __bf16 ent_s[L_DIM * LDP];
    __shared__ float wave_sum[4];

    // acc[rt][ct]: rows wave*32 + rt*16 + quad*4 + reg, col ct*16 + (lane&15)
    f32x4 acc[2][8];
    const f32x4 zero = {0.f, 0.f, 0.f, 0.f};
#pragma unroll
    for (int rt = 0; rt < 2; ++rt)
#pragma unroll
        for (int ct = 0; ct < 8; ++ct)
            acc[rt][ct] = zero;

    for (int c = 0; c < D_DIM / DC; ++c) {
        __syncthreads();   // previous chunk's compute done before overwrite
        // ---- stage chunk: 128 rows x 64 cols of ctx and ent, fp32 -> bf16 ----
        // 2048 float4 per array; 256 threads x 8 each.
#pragma unroll 2
        for (int i = 0; i < 8; ++i) {
            const int g   = t + i * 256;      // 0..2047
            const int row = g >> 4;           // 0..127
            const int c4  = g & 15;           // float4 index within the 64-col chunk
            const int goff = row * D_DIM + c * DC + c4 * 4;
            const float4 vc = *(const float4*)(ctx_g + goff);
            const float4 ve = *(const float4*)(ent_g + goff);
            bf16x4 pc = {(__bf16)vc.x, (__bf16)vc.y, (__bf16)vc.z, (__bf16)vc.w};
            bf16x4 pe = {(__bf16)ve.x, (__bf16)ve.y, (__bf16)ve.z, (__bf16)ve.w};
            *(bf16x4*)&ctx_s[row * LDP + c4 * 4] = pc;
            *(bf16x4*)&ent_s[row * LDP + c4 * 4] = pe;
        }
        __syncthreads();

        // ---- MFMA: each wave does rows [wave*32, wave*32+32) x all 128 cols ----
#pragma unroll
        for (int ks = 0; ks < 2; ++ks) {
            // A frag: A[m = lane&15][k = quad*8 + j]
            const bf16x8 a0 = *(const bf16x8*)&ctx_s[(wave * 32 + l15) * LDP + ks * 32 + quad * 8];
            const bf16x8 a1 = *(const bf16x8*)&ctx_s[(wave * 32 + 16 + l15) * LDP + ks * 32 + quad * 8];
#pragma unroll
            for (int ct = 0; ct < 8; ++ct) {
                // B frag: B[n = lane&15][k = quad*8 + j]  (C = A * B^T pattern: same load as A)
                const bf16x8 b = *(const bf16x8*)&ent_s[(ct * 16 + l15) * LDP + ks * 32 + quad * 8];
                acc[0][ct] = __builtin_amdgcn_mfma_f32_16x16x32_bf16(a0, b, acc[0][ct], 0, 0, 0);
                acc[1][ct] = __builtin_amdgcn_mfma_f32_16x16x32_bf16(a1, b, acc[1][ct], 0, 0, 0);
            }
        }
    }

    // ---- epilogue: row-max over 128 cols, then sum of maxes ----
    // C/D layout: col = ct*16 + (lane&15), row = rt*16 + quad*4 + reg.
    float total = 0.f;
#pragma unroll
    for (int rt = 0; rt < 2; ++rt) {
#pragma unroll
        for (int reg = 0; reg < 4; ++reg) {
            float m = acc[rt][0][reg];
#pragma unroll
            for (int ct = 1; ct < 8; ++ct) m = fmaxf(m, acc[rt][ct][reg]);
            // max across the 16 lanes of this quad (cols 0..15 within each tile)
            m = fmaxf(m, __shfl_xor(m, 1, 64));
            m = fmaxf(m, __shfl_xor(m, 2, 64));
            m = fmaxf(m, __shfl_xor(m, 4, 64));
            m = fmaxf(m, __shfl_xor(m, 8, 64));
            total += m;   // every lane of the quad now holds this row's max
        }
    }
    // total (per lane) = sum of the 8 rows owned by this quad; combine quads
    total += __shfl_xor(total, 16, 64);
    total += __shfl_xor(total, 32, 64);

    if (lane == 0) wave_sum[wave] = total;
    __syncthreads();
    if (t == 0)
        out[bk] = wave_sum[0] + wave_sum[1] + wave_sum[2] + wave_sum[3];
}

extern "C" void kernel_launch(void* const* d_in, const int* in_sizes, int n_in,
                              void* d_out, int out_size, void* d_ws, size_t ws_size,
                              hipStream_t stream) {
    const float* context = (const float*)d_in[0];
    float* out = (float*)d_out;
    som_kernel<<<dim3(1024), dim3(256), 0, stream>>>(context, out);
}